// Round 19
// baseline (142.774 us; speedup 1.0000x reference)
//
#include <hip/hip_runtime.h>
#include <hip/hip_bf16.h>

#define BATCH 4
#define CCH   256
#define HH    128
#define WW    128
#define HWSZ  (HH * WW)         // 16384
#define NHEADS 4
#define DHEAD 64
#define KDIM  256
#define PDIM  16384

typedef unsigned short u16;
typedef short bf16x8 __attribute__((ext_vector_type(8)));
typedef float f32x4  __attribute__((ext_vector_type(4)));

__device__ __forceinline__ float bf2f(u16 u) {
    return __uint_as_float(((unsigned)u) << 16);
}
__device__ __forceinline__ u16 f2bf(float f) {
    unsigned u = __float_as_uint(f);
    unsigned r = (u + 0x7fffu + ((u >> 16) & 1u)) >> 16;
    return (u16)r;
}
__device__ __forceinline__ unsigned pack2(float a, float b) {
    return (unsigned)f2bf(a) | ((unsigned)f2bf(b) << 16);
}
__device__ __forceinline__ void gl_lds16(const u16* g, u16* l) {
    __builtin_amdgcn_global_load_lds(
        (const __attribute__((address_space(1))) void*)g,
        (__attribute__((address_space(3))) void*)l, 16, 0, 0);
}

// ---------------------------------------------------------------------------
// Transpose + convert: x [b][c][p] fp32 -> XT [b][p][c] bf16. 32x32 tiles.
// ALSO converts both weight matrices to bf16 (first 256 blocks of the
// y==0, z==0 plane each handle one 1024-float chunk).
// ---------------------------------------------------------------------------
__global__ __launch_bounds__(256) void transpose_x(
    const float* __restrict__ x, u16* __restrict__ XT,
    const float* __restrict__ wq, const float* __restrict__ wp,
    u16* __restrict__ wqb, u16* __restrict__ wpb)
{
    __shared__ float t[32][33];
    const int b  = blockIdx.z;
    const int c0 = blockIdx.y * 32;
    const int p0 = blockIdx.x * 32;
    const int tid = threadIdx.x;

    if (b == 0 && blockIdx.y == 0 && blockIdx.x < 256) {
        const int i = (blockIdx.x * 256 + tid) * 4;   // < 262144
        const float4 v = (i < 196608)
            ? *reinterpret_cast<const float4*>(&wq[i])
            : *reinterpret_cast<const float4*>(&wp[i - 196608]);
        ushort4 o;
        o.x = f2bf(v.x); o.y = f2bf(v.y); o.z = f2bf(v.z); o.w = f2bf(v.w);
        if (i < 196608) *reinterpret_cast<ushort4*>(&wqb[i]) = o;
        else            *reinterpret_cast<ushort4*>(&wpb[i - 196608]) = o;
    }

    #pragma unroll
    for (int it = 0; it < 4; ++it) {
        const int r = it * 8 + (tid >> 5);
        const int col = tid & 31;
        t[r][col] = x[((size_t)b * CCH + c0 + r) * HWSZ + p0 + col];
    }
    __syncthreads();
    #pragma unroll
    for (int it = 0; it < 2; ++it) {
        const int prow = it * 16 + (tid >> 4);
        const int cpair = (tid & 15) * 2;
        const float v0 = t[cpair][prow];
        const float v1 = t[cpair + 1][prow];
        ushort2 o; o.x = f2bf(v0); o.y = f2bf(v1);
        *reinterpret_cast<ushort2*>(
            &XT[((size_t)b * HWSZ + p0 + prow) * CCH + c0 + cpair]) = o;
    }
}

// ---------------------------------------------------------------------------
// QKV MFMA GEMM: D[o][p] = sum_k WQ[o][k] * XT[p][k]  (bf16, k-contiguous)
// K=256, BK=64, tile 128x128, 4 waves (2x2), mfma_f32_16x16x32_bf16.
// DOUBLE-BUFFERED LDS (2 x 32 KB): stage(kt+1) is issued BEFORE compute(kt)
// so global_load_lds latency hides under the MFMA phase (T3 2-phase recipe);
// one barrier per K-step. XCD-aware p-tile swizzle. Epilogue: C-tile ->
// LDS Ct[2][128][72] (aliases buffers) -> coalesced 16B stores into
// QKVH [(z*4+head)][p][q64|k64|v64].
// ---------------------------------------------------------------------------
__global__ __launch_bounds__(256) void gemm_qkv(
    const u16* __restrict__ A, const u16* __restrict__ B,
    u16* __restrict__ QKVH, long long b_zs)
{
    constexpr int BK = 64;
    constexpr int CTP = 72;               // Ct row stride (u16): 144B
    __shared__ __align__(16) u16 lds[32768];  // 65536 B: 2 x (As 16KB + Bs 16KB)

    const int tid  = threadIdx.x;
    const int lane = tid & 63;
    const int w    = tid >> 6;
    const int wm   = w >> 1, wn = w & 1;
    const int o0   = blockIdx.y * 128;
    const int pt   = ((blockIdx.x & 7) << 4) | (blockIdx.x >> 3);  // bijective
    const int p0   = pt * 128;
    const int z    = blockIdx.z;
    const u16* Bz  = B + (size_t)z * b_zs;

    const int srow  = lane >> 3;
    const int sslot = (lane & 7) ^ srow;

    auto stage = [&](int c0, int buf) {
        u16* As = lds + buf * 16384;
        u16* Bs = As + 8192;
        #pragma unroll
        for (int j = 0; j < 4; ++j) {
            const int q = w * 4 + j;
            const int r = q * 8 + srow;
            gl_lds16(A  + (size_t)(o0 + r) * KDIM + c0 + sslot * 8, As + q * 512);
            gl_lds16(Bz + (size_t)(p0 + r) * KDIM + c0 + sslot * 8, Bs + q * 512);
        }
    };

    f32x4 acc[4][4];
    #pragma unroll
    for (int m = 0; m < 4; ++m)
        #pragma unroll
        for (int n = 0; n < 4; ++n)
            acc[m][n] = (f32x4){0.f, 0.f, 0.f, 0.f};

    stage(0, 0);
    int cur = 0;
    #pragma unroll
    for (int kt = 0; kt < KDIM / BK; ++kt) {
        __syncthreads();                  // drains stage(cur); frees cur^1
        if (kt + 1 < KDIM / BK)
            stage((kt + 1) * BK, cur ^ 1);   // loads overlap compute below
        const u16* As = lds + cur * 16384;
        const u16* Bs = As + 8192;
        #pragma unroll
        for (int h = 0; h < 2; ++h) {
            bf16x8 af[4], bfr[4];
            #pragma unroll
            for (int m = 0; m < 4; ++m) {
                const int r  = wm * 64 + m * 16 + (lane & 15);
                const int sl = ((h << 2) | (lane >> 4)) ^ (r & 7);
                af[m] = *reinterpret_cast<const bf16x8*>(As + r * BK + sl * 8);
            }
            #pragma unroll
            for (int n = 0; n < 4; ++n) {
                const int r  = wn * 64 + n * 16 + (lane & 15);
                const int sl = ((h << 2) | (lane >> 4)) ^ (r & 7);
                bfr[n] = *reinterpret_cast<const bf16x8*>(Bs + r * BK + sl * 8);
            }
            #pragma unroll
            for (int m = 0; m < 4; ++m)
                #pragma unroll
                for (int n = 0; n < 4; ++n)
                    acc[m][n] = __builtin_amdgcn_mfma_f32_16x16x32_bf16(
                        af[m], bfr[n], acc[m][n], 0, 0, 0);
        }
        cur ^= 1;
    }

    // Epilogue: acc -> LDS Ct[2][128][CTP] u16 (slice = wm), pixel-major.
    __syncthreads();                      // all LDS reads done, safe to reuse
    u16* Ct = lds;                        // 2*128*72*2 = 36864 B (< 65536)
    const int g = lane >> 4, ln15 = lane & 15;
    #pragma unroll
    for (int m = 0; m < 4; ++m) {
        const int och = m * 16 + g * 4;   // within-slice channel (j packed)
        #pragma unroll
        for (int n = 0; n < 4; ++n) {
            const int px = wn * 64 + n * 16 + ln15;
            uint2 w2;
            w2.x = pack2(acc[m][n][0], acc[m][n][1]);
            w2.y = pack2(acc[m][n][2], acc[m][n][3]);
            *reinterpret_cast<uint2*>(&Ct[(wm * 128 + px) * CTP + och]) = w2;
        }
    }
    __syncthreads();

    // Coalesced store: full coverage 2 slices x 128 px x 8 chunks.
    const int c   = tid & 7;              // 16B chunk within 64-ch slice
    const int sl  = (tid >> 3) & 1;       // slice (o0 + sl*64)
    const int px0 = tid >> 4;             // 0..15
    const int abs_slice = blockIdx.y * 2 + sl;   // 0..11
    const int qkv  = abs_slice >> 2;
    const int head = abs_slice & 3;
    u16* dbase = QKVH + ((size_t)(z * NHEADS + head) * HWSZ) * 192 + qkv * 64 + c * 8;
    #pragma unroll
    for (int pass = 0; pass < 8; ++pass) {
        const int px = px0 + pass * 16;
        const uint4 val = *reinterpret_cast<const uint4*>(
            &Ct[(sl * 128 + px) * CTP + c * 8]);
        *reinterpret_cast<uint4*>(dbase + (size_t)(p0 + px) * 192) = val;
    }
}

// ---------------------------------------------------------------------------
// Dilated neighborhood attention on QKVH [(z*4+head)][p][q64|k64|v64] bf16.
// 8 threads per position (8 channels each); scores combined via
// __shfl_xor(.,1/2/4); softmax redundant per octet; PV per 8 channels.
// k loads batch-issued; v loads issued before softmax (latency hiding).
// XCD-aware blockIdx.x swizzle. OOB: score exactly 0 in softmax, zero v.
// ---------------------------------------------------------------------------
__global__ __launch_bounds__(256) void attn8(
    const u16* __restrict__ QKVH, u16* __restrict__ YT)
{
    const int hi  = blockIdx.y;
    const int tid = threadIdx.x;
    const int bxr = blockIdx.x;                       // 0..511
    const int bx  = (bxr & 7) * 64 + (bxr >> 3);      // XCD-contiguous bands
    const int p   = bx * 32 + (tid >> 3);
    const int oct = tid & 7;                          // 8-ch slice
    const int yy = p >> 7;
    const int xx = p & 127;
    const int r  = hi + 1;

    const u16* base = QKVH +
        ((size_t)(blockIdx.z * NHEADS + hi) * HWSZ) * 192;

    // q octet (8 channels) -> fp32 regs
    const uint4 qv = *reinterpret_cast<const uint4*>(
        base + (size_t)p * 192 + oct * 8);
    float qf[8];
    {
        const unsigned wv[4] = {qv.x, qv.y, qv.z, qv.w};
        #pragma unroll
        for (int d = 0; d < 4; ++d) {
            qf[d * 2 + 0] = __uint_as_float(wv[d] << 16);
            qf[d * 2 + 1] = __uint_as_float(wv[d] & 0xffff0000u);
        }
    }

    int   offs[9];
    float valid[9];
    #pragma unroll
    for (int n = 0; n < 9; ++n) {
        const int dy = (n / 3 - 1) * r;
        const int dx = (n % 3 - 1) * r;
        const int y2 = yy + dy, x2 = xx + dx;
        const bool ok = (y2 >= 0) && (y2 < HH) && (x2 >= 0) && (x2 < WW);
        valid[n] = ok ? 1.f : 0.f;
        const int y2c = min(max(y2, 0), HH - 1);
        const int x2c = min(max(x2, 0), WW - 1);
        offs[n] = y2c * WW + x2c;
    }

    // Batch-issue all 9 k loads (independent -> 9 outstanding VMEM ops)
    uint4 kb[9];
    #pragma unroll
    for (int n = 0; n < 9; ++n)
        kb[n] = *reinterpret_cast<const uint4*>(
            base + (size_t)offs[n] * 192 + 64 + oct * 8);

    float sc[9];
    #pragma unroll
    for (int n = 0; n < 9; ++n) {
        const unsigned wv[4] = {kb[n].x, kb[n].y, kb[n].z, kb[n].w};
        float s = 0.f;
        #pragma unroll
        for (int d = 0; d < 4; ++d) {
            s += qf[d * 2 + 0] * __uint_as_float(wv[d] << 16);
            s += qf[d * 2 + 1] * __uint_as_float(wv[d] & 0xffff0000u);
        }
        sc[n] = s;
    }
    #pragma unroll
    for (int n = 0; n < 9; ++n) {
        sc[n] += __shfl_xor(sc[n], 1);
        sc[n] += __shfl_xor(sc[n], 2);
        sc[n] += __shfl_xor(sc[n], 4);
        sc[n] *= valid[n];
    }

    // Issue all 9 v loads NOW — latency hides under the softmax below.
    uint4 vb[9];
    #pragma unroll
    for (int n = 0; n < 9; ++n)
        vb[n] = *reinterpret_cast<const uint4*>(
            base + (size_t)offs[n] * 192 + 128 + oct * 8);

    float m = sc[0];
    #pragma unroll
    for (int n = 1; n < 9; ++n) m = fmaxf(m, sc[n]);
    float wgt[9], den = 0.f;
    #pragma unroll
    for (int n = 0; n < 9; ++n) { wgt[n] = __expf(sc[n] - m); den += wgt[n]; }
    const float inv = 1.f / den;
    #pragma unroll
    for (int n = 0; n < 9; ++n) wgt[n] *= inv * valid[n];

    // PV for this thread's 8 channels
    float a[8];
    #pragma unroll
    for (int d = 0; d < 8; ++d) a[d] = 0.f;
    #pragma unroll
    for (int n = 0; n < 9; ++n) {
        const unsigned wv[4] = {vb[n].x, vb[n].y, vb[n].z, vb[n].w};
        const float wn_ = wgt[n];
        #pragma unroll
        for (int d = 0; d < 4; ++d) {
            a[d * 2 + 0] += wn_ * __uint_as_float(wv[d] << 16);
            a[d * 2 + 1] += wn_ * __uint_as_float(wv[d] & 0xffff0000u);
        }
    }

    u16* outp = YT + ((size_t)blockIdx.z * HWSZ + p) * CCH
                   + hi * DHEAD + oct * 8;
    uint4 st;
    st.x = pack2(a[0], a[1]);
    st.y = pack2(a[2], a[3]);
    st.z = pack2(a[4], a[5]);
    st.w = pack2(a[6], a[7]);
    *reinterpret_cast<uint4*>(outp) = st;
}

// ---------------------------------------------------------------------------
// Proj MFMA GEMM + fused BN partials: D[o][p] = sum_k WP[o][k] * YT[p][k].
// DOUBLE-BUFFERED LDS (same T3 2-phase structure as gemm_qkv).
// XCD-aware p-tile swizzle. Writes YP bf16 [batch][o][p] and per-(channel,
// 64px-block) (sum,sumsq) partials (slot = swizzled tile, bijective).
// ---------------------------------------------------------------------------
__global__ __launch_bounds__(256) void gemm_proj(
    const u16* __restrict__ A, const u16* __restrict__ B,
    u16* __restrict__ YP, long long b_zs,
    float* __restrict__ part, int batch0)
{
    constexpr int BK = 64;
    __shared__ __align__(16) u16 lds[32768];  // 65536 B: 2 x (As + Bs)

    const int tid  = threadIdx.x;
    const int lane = tid & 63;
    const int w    = tid >> 6;
    const int wm   = w >> 1, wn = w & 1;
    const int o0   = blockIdx.y * 128;
    const int pt   = ((blockIdx.x & 7) << 4) | (blockIdx.x >> 3);  // bijective
    const int p0   = pt * 128;
    const u16* Bz  = B + (size_t)blockIdx.z * b_zs;

    const int srow  = lane >> 3;
    const int sslot = (lane & 7) ^ srow;

    auto stage = [&](int c0, int buf) {
        u16* As = lds + buf * 16384;
        u16* Bs = As + 8192;
        #pragma unroll
        for (int j = 0; j < 4; ++j) {
            const int q = w * 4 + j;
            const int r = q * 8 + srow;
            gl_lds16(A  + (size_t)(o0 + r) * KDIM + c0 + sslot * 8, As + q * 512);
            gl_lds16(Bz + (size_t)(p0 + r) * KDIM + c0 + sslot * 8, Bs + q * 512);
        }
    };

    f32x4 acc[4][4];
    #pragma unroll
    for (int m = 0; m < 4; ++m)
        #pragma unroll
        for (int n = 0; n < 4; ++n)
            acc[m][n] = (f32x4){0.f, 0.f, 0.f, 0.f};

    stage(0, 0);
    int cur = 0;
    #pragma unroll
    for (int kt = 0; kt < KDIM / BK; ++kt) {
        __syncthreads();
        if (kt + 1 < KDIM / BK)
            stage((kt + 1) * BK, cur ^ 1);
        const u16* As = lds + cur * 16384;
        const u16* Bs = As + 8192;
        #pragma unroll
        for (int h = 0; h < 2; ++h) {
            bf16x8 af[4], bfr[4];
            #pragma unroll
            for (int m = 0; m < 4; ++m) {
                const int r  = wm * 64 + m * 16 + (lane & 15);
                const int sl = ((h << 2) | (lane >> 4)) ^ (r & 7);
                af[m] = *reinterpret_cast<const bf16x8*>(As + r * BK + sl * 8);
            }
            #pragma unroll
            for (int n = 0; n < 4; ++n) {
                const int r  = wn * 64 + n * 16 + (lane & 15);
                const int sl = ((h << 2) | (lane >> 4)) ^ (r & 7);
                bfr[n] = *reinterpret_cast<const bf16x8*>(Bs + r * BK + sl * 8);
            }
            #pragma unroll
            for (int m = 0; m < 4; ++m)
                #pragma unroll
                for (int n = 0; n < 4; ++n)
                    acc[m][n] = __builtin_amdgcn_mfma_f32_16x16x32_bf16(
                        af[m], bfr[n], acc[m][n], 0, 0, 0);
        }
        cur ^= 1;
    }

    const int g = lane >> 4, ln15 = lane & 15;
    const int batch = batch0 + blockIdx.z;
    u16* Yz = YP + (size_t)batch * CCH * HWSZ;
    float s[4][4], q2[4][4];
    #pragma unroll
    for (int m = 0; m < 4; ++m) {
        const int ow = o0 + wm * 64 + m * 16 + g * 4;
        #pragma unroll
        for (int j = 0; j < 4; ++j) { s[m][j] = 0.f; q2[m][j] = 0.f; }
        #pragma unroll
        for (int n = 0; n < 4; ++n) {
            const int pc = p0 + wn * 64 + n * 16 + ln15;
            #pragma unroll
            for (int j = 0; j < 4; ++j) {
                const float v = acc[m][n][j];
                Yz[(size_t)(ow + j) * PDIM + pc] = f2bf(v);
                s[m][j]  += v;
                q2[m][j] += v * v;
            }
        }
    }
    // reduce over the 16 px-lanes (bits 0..3 of lane)
    #pragma unroll
    for (int mask = 1; mask <= 8; mask <<= 1) {
        #pragma unroll
        for (int m = 0; m < 4; ++m)
            #pragma unroll
            for (int j = 0; j < 4; ++j) {
                s[m][j]  += __shfl_xor(s[m][j],  mask);
                q2[m][j] += __shfl_xor(q2[m][j], mask);
            }
    }
    if (ln15 == 0) {
        const int pxblk = batch * 256 + pt * 2 + wn;   // 64-px block (bijective)
        #pragma unroll
        for (int m = 0; m < 4; ++m) {
            const int ow = o0 + wm * 64 + m * 16 + g * 4;
            #pragma unroll
            for (int j = 0; j < 4; ++j) {
                const size_t idx = ((size_t)(ow + j) * 1024 + pxblk) * 2;
                part[idx]     = s[m][j];
                part[idx + 1] = q2[m][j];
            }
        }
    }
}

// ---------------------------------------------------------------------------
// BN final: per channel, reduce 1024 (sum,sumsq) partials. Deterministic.
// ---------------------------------------------------------------------------
__global__ __launch_bounds__(256) void bn_final(
    const float* __restrict__ part, float* __restrict__ stats)
{
    const int c = blockIdx.x;
    const int tid = threadIdx.x;
    float s = 0.f, q = 0.f;
    #pragma unroll
    for (int it = 0; it < 4; ++it) {
        const int i = tid + it * 256;
        s += part[((size_t)c * 1024 + i) * 2 + 0];
        q += part[((size_t)c * 1024 + i) * 2 + 1];
    }
    __shared__ float sh0[256], sh1[256];
    sh0[tid] = s; sh1[tid] = q;
    __syncthreads();
    for (int st = 128; st > 0; st >>= 1) {
        if (tid < st) { sh0[tid] += sh0[tid + st]; sh1[tid] += sh1[tid + st]; }
        __syncthreads();
    }
    if (tid == 0) {
        const float N = (float)(BATCH * HWSZ);
        const float mean = sh0[0] / N;
        const float var  = sh1[0] / N - mean * mean;
        stats[c]       = mean;
        stats[CCH + c] = rsqrtf(var + 1e-5f);
    }
}

// ---------------------------------------------------------------------------
// Epilogue: out = x + silu( (yp - mean) * invstd * gamma + beta ), yp bf16.
// ---------------------------------------------------------------------------
__global__ __launch_bounds__(256) void bn_silu_res(
    const u16* __restrict__ yp, const float* __restrict__ x,
    const float* __restrict__ stats, const float* __restrict__ gamma,
    const float* __restrict__ beta, float* __restrict__ out)
{
    const size_t i = ((size_t)blockIdx.x * 256 + threadIdx.x) * 8;
    const int c = (int)((i >> 14) & 255);
    const float mean = stats[c];
    const float inv  = stats[CCH + c];
    const float g = gamma[c], bt = beta[c];

    const uint4 yv = *reinterpret_cast<const uint4*>(&yp[i]);
    const unsigned wv[4] = {yv.x, yv.y, yv.z, yv.w};
    float vo[8];
    #pragma unroll
    for (int d = 0; d < 4; ++d) {
        const float y0 = __uint_as_float(wv[d] << 16);
        const float y1 = __uint_as_float(wv[d] & 0xffff0000u);
        const float yn0 = (y0 - mean) * inv * g + bt;
        const float yn1 = (y1 - mean) * inv * g + bt;
        vo[d * 2 + 0] = yn0 / (1.f + __expf(-yn0));
        vo[d * 2 + 1] = yn1 / (1.f + __expf(-yn1));
    }
    const float4 x0 = *reinterpret_cast<const float4*>(&x[i]);
    const float4 x1 = *reinterpret_cast<const float4*>(&x[i + 4]);
    float4 o0, o1;
    o0.x = x0.x + vo[0]; o0.y = x0.y + vo[1];
    o0.z = x0.z + vo[2]; o0.w = x0.w + vo[3];
    o1.x = x1.x + vo[4]; o1.y = x1.y + vo[5];
    o1.z = x1.z + vo[6]; o1.w = x1.w + vo[7];
    *reinterpret_cast<float4*>(&out[i])     = o0;
    *reinterpret_cast<float4*>(&out[i + 4]) = o1;
}

// ---------------------------------------------------------------------------
extern "C" void kernel_launch(void* const* d_in, const int* in_sizes, int n_in,
                              void* d_out, int out_size, void* d_ws, size_t ws_size,
                              hipStream_t stream)
{
    const float* x      = (const float*)d_in[0];
    const float* w_qkv  = (const float*)d_in[1];
    const float* w_proj = (const float*)d_in[2];
    const float* gamma  = (const float*)d_in[3];
    const float* beta   = (const float*)d_in[4];
    float* out = (float*)d_out;

    // ws layout:
    //   XT [4][16384][256] bf16 (33.5 MB); YP aliases it (XT is fully dead
    //   once gemm_qkv for those batches has consumed it).
    //   QKVH: [z*4 heads][16384][192]; YT follows QKVH.
    //   Full path (z=4, single pass): 170.4 MB. Pair path (z=2): ~103 MB.
    u16*   XT    = (u16*)d_ws;
    u16*   YP    = XT;                               // alias (see above)
    u16*   WQb   = XT + (size_t)BATCH * HWSZ * CCH;  // [768][256]
    u16*   WPb   = WQb + 768 * CCH;                  // [256][256]
    float* part  = (float*)(WPb + CCH * CCH);        // [256][1024][2] = 2 MB
    float* stats = part + (size_t)CCH * 1024 * 2;    // [512]
    u16*   QKVH  = (u16*)(stats + 512);

    const size_t qkvh_full = (size_t)BATCH * NHEADS * HWSZ * 192;   // 4 batches
    const size_t yt_full   = (size_t)BATCH * HWSZ * CCH;
    u16* YT_full = QKVH + qkvh_full;
    u16* YT_pair = QKVH + qkvh_full / 2;

    const size_t need_full =
        (size_t)((char*)(YT_full + yt_full) - (char*)d_ws);

    // 1) x -> XT (transpose + bf16) with fused weight conversion
    transpose_x<<<dim3(HWSZ / 32, CCH / 32, BATCH), 256, 0, stream>>>(
        x, XT, w_qkv, w_proj, WQb, WPb);

    if (ws_size >= need_full) {
        // 2a) Single pass, z = 4: QKV GEMM -> attention -> proj (+BN partials)
        gemm_qkv<<<dim3(PDIM / 128, 768 / 128, BATCH), 256, 0, stream>>>(
            WQb, XT, QKVH, (long long)HWSZ * CCH);

        attn8<<<dim3(HWSZ / 32, NHEADS, BATCH), 256, 0, stream>>>(QKVH, YT_full);

        gemm_proj<<<dim3(PDIM / 128, CCH / 128, BATCH), 256, 0, stream>>>(
            WPb, YT_full, YP, (long long)HWSZ * CCH, part, 0);
    } else {
        // 2b) Two passes of batch pairs (z = 2), QKVH/YT regions reused.
        for (int pair = 0; pair < 2; ++pair) {
            const u16* Bx = XT + (size_t)pair * 2 * HWSZ * CCH;
            gemm_qkv<<<dim3(PDIM / 128, 768 / 128, 2), 256, 0, stream>>>(
                WQb, Bx, QKVH, (long long)HWSZ * CCH);

            attn8<<<dim3(HWSZ / 32, NHEADS, 2), 256, 0, stream>>>(QKVH, YT_pair);

            gemm_proj<<<dim3(PDIM / 128, CCH / 128, 2), 256, 0, stream>>>(
                WPb, YT_pair, YP, (long long)HWSZ * CCH, part, pair * 2);
        }
    }

    // 3) BN stats from fused partials
    bn_final<<<CCH, 256, 0, stream>>>(part, stats);

    // 4) BN + SiLU + residual: out = x + silu(bn(YP))
    bn_silu_res<<<(unsigned)((size_t)BATCH * CCH * HWSZ / 8 / 256), 256, 0, stream>>>(
        YP, x, stats, gamma, beta, out);
}

// Round 20
// 136.358 us; speedup vs baseline: 1.0471x; 1.0471x over previous
//
#include <hip/hip_runtime.h>
#include <hip/hip_bf16.h>

#define BATCH 4
#define CCH   256
#define HH    128
#define WW    128
#define HWSZ  (HH * WW)         // 16384
#define NHEADS 4
#define DHEAD 64
#define KDIM  256
#define PDIM  16384

typedef unsigned short u16;
typedef short bf16x8 __attribute__((ext_vector_type(8)));
typedef float f32x4  __attribute__((ext_vector_type(4)));

__device__ __forceinline__ float bf2f(u16 u) {
    return __uint_as_float(((unsigned)u) << 16);
}
__device__ __forceinline__ u16 f2bf(float f) {
    unsigned u = __float_as_uint(f);
    unsigned r = (u + 0x7fffu + ((u >> 16) & 1u)) >> 16;
    return (u16)r;
}
__device__ __forceinline__ unsigned pack2(float a, float b) {
    return (unsigned)f2bf(a) | ((unsigned)f2bf(b) << 16);
}
__device__ __forceinline__ void gl_lds16(const u16* g, u16* l) {
    __builtin_amdgcn_global_load_lds(
        (const __attribute__((address_space(1))) void*)g,
        (__attribute__((address_space(3))) void*)l, 16, 0, 0);
}

// ---------------------------------------------------------------------------
// Transpose + convert: x [b][c][p] fp32 -> XT [b][p][c] bf16. 32x32 tiles.
// ALSO converts both weight matrices to bf16 (first 256 blocks of the
// y==0, z==0 plane each handle one 1024-float chunk).
// ---------------------------------------------------------------------------
__global__ __launch_bounds__(256) void transpose_x(
    const float* __restrict__ x, u16* __restrict__ XT,
    const float* __restrict__ wq, const float* __restrict__ wp,
    u16* __restrict__ wqb, u16* __restrict__ wpb)
{
    __shared__ float t[32][33];
    const int b  = blockIdx.z;
    const int c0 = blockIdx.y * 32;
    const int p0 = blockIdx.x * 32;
    const int tid = threadIdx.x;

    if (b == 0 && blockIdx.y == 0 && blockIdx.x < 256) {
        const int i = (blockIdx.x * 256 + tid) * 4;   // < 262144
        const float4 v = (i < 196608)
            ? *reinterpret_cast<const float4*>(&wq[i])
            : *reinterpret_cast<const float4*>(&wp[i - 196608]);
        ushort4 o;
        o.x = f2bf(v.x); o.y = f2bf(v.y); o.z = f2bf(v.z); o.w = f2bf(v.w);
        if (i < 196608) *reinterpret_cast<ushort4*>(&wqb[i]) = o;
        else            *reinterpret_cast<ushort4*>(&wpb[i - 196608]) = o;
    }

    #pragma unroll
    for (int it = 0; it < 4; ++it) {
        const int r = it * 8 + (tid >> 5);
        const int col = tid & 31;
        t[r][col] = x[((size_t)b * CCH + c0 + r) * HWSZ + p0 + col];
    }
    __syncthreads();
    #pragma unroll
    for (int it = 0; it < 2; ++it) {
        const int prow = it * 16 + (tid >> 4);
        const int cpair = (tid & 15) * 2;
        const float v0 = t[cpair][prow];
        const float v1 = t[cpair + 1][prow];
        ushort2 o; o.x = f2bf(v0); o.y = f2bf(v1);
        *reinterpret_cast<ushort2*>(
            &XT[((size_t)b * HWSZ + p0 + prow) * CCH + c0 + cpair]) = o;
    }
}

// ---------------------------------------------------------------------------
// QKV MFMA GEMM: D[o][p] = sum_k WQ[o][k] * XT[p][k]  (bf16, k-contiguous)
// K=256, BK=64, tile 128x128, 4 waves (2x2), mfma_f32_16x16x32_bf16.
// XCD-aware p-tile swizzle. Epilogue: C-tile -> LDS Ct[2][128][72] ->
// coalesced 16B stores into QKVH [(z*4+head)][p][q64|k64|v64].
// (Round-18 proven configuration: single buffer, 36864 B LDS, 2 barriers.)
// ---------------------------------------------------------------------------
__global__ __launch_bounds__(256) void gemm_qkv(
    const u16* __restrict__ A, const u16* __restrict__ B,
    u16* __restrict__ QKVH, long long b_zs)
{
    constexpr int BK = 64;
    constexpr int CTP = 72;               // Ct row stride (u16): 144B, 16B mult
    __shared__ __align__(16) u16 lds[18432];  // 36864 B union
    u16* As = lds;                        // 8192 u16
    u16* Bs = lds + 8192;                 // 8192 u16

    const int tid  = threadIdx.x;
    const int lane = tid & 63;
    const int w    = tid >> 6;
    const int wm   = w >> 1, wn = w & 1;
    const int o0   = blockIdx.y * 128;
    const int pt   = ((blockIdx.x & 7) << 4) | (blockIdx.x >> 3);  // bijective
    const int p0   = pt * 128;
    const int z    = blockIdx.z;
    const u16* Bz  = B + (size_t)z * b_zs;

    const int srow  = lane >> 3;
    const int sslot = (lane & 7) ^ srow;

    auto stage = [&](int c0) {
        #pragma unroll
        for (int j = 0; j < 4; ++j) {
            const int q = w * 4 + j;
            const int r = q * 8 + srow;
            gl_lds16(A  + (size_t)(o0 + r) * KDIM + c0 + sslot * 8, As + q * 512);
            gl_lds16(Bz + (size_t)(p0 + r) * KDIM + c0 + sslot * 8, Bs + q * 512);
        }
    };

    f32x4 acc[4][4];
    #pragma unroll
    for (int m = 0; m < 4; ++m)
        #pragma unroll
        for (int n = 0; n < 4; ++n)
            acc[m][n] = (f32x4){0.f, 0.f, 0.f, 0.f};

    stage(0);
    #pragma unroll
    for (int kt = 0; kt < KDIM / BK; ++kt) {
        __syncthreads();
        #pragma unroll
        for (int h = 0; h < 2; ++h) {
            bf16x8 af[4], bfr[4];
            #pragma unroll
            for (int m = 0; m < 4; ++m) {
                const int r  = wm * 64 + m * 16 + (lane & 15);
                const int sl = ((h << 2) | (lane >> 4)) ^ (r & 7);
                af[m] = *reinterpret_cast<const bf16x8*>(As + r * BK + sl * 8);
            }
            #pragma unroll
            for (int n = 0; n < 4; ++n) {
                const int r  = wn * 64 + n * 16 + (lane & 15);
                const int sl = ((h << 2) | (lane >> 4)) ^ (r & 7);
                bfr[n] = *reinterpret_cast<const bf16x8*>(Bs + r * BK + sl * 8);
            }
            #pragma unroll
            for (int m = 0; m < 4; ++m)
                #pragma unroll
                for (int n = 0; n < 4; ++n)
                    acc[m][n] = __builtin_amdgcn_mfma_f32_16x16x32_bf16(
                        af[m], bfr[n], acc[m][n], 0, 0, 0);
        }
        if (kt + 1 < KDIM / BK) {
            __syncthreads();
            stage((kt + 1) * BK);
        }
    }

    // Epilogue: acc -> LDS Ct[2][128][CTP] u16 (slice = wm), pixel-major.
    __syncthreads();                      // all LDS reads done, safe to reuse
    u16* Ct = lds;                        // 2*128*72*2 = 36864 B
    const int g = lane >> 4, ln15 = lane & 15;
    #pragma unroll
    for (int m = 0; m < 4; ++m) {
        const int och = m * 16 + g * 4;   // within-slice channel (j packed)
        #pragma unroll
        for (int n = 0; n < 4; ++n) {
            const int px = wn * 64 + n * 16 + ln15;
            uint2 w2;
            w2.x = pack2(acc[m][n][0], acc[m][n][1]);
            w2.y = pack2(acc[m][n][2], acc[m][n][3]);
            *reinterpret_cast<uint2*>(&Ct[(wm * 128 + px) * CTP + och]) = w2;
        }
    }
    __syncthreads();

    // Coalesced store: full coverage 2 slices x 128 px x 8 chunks.
    const int c   = tid & 7;              // 16B chunk within 64-ch slice
    const int sl  = (tid >> 3) & 1;       // slice (o0 + sl*64)
    const int px0 = tid >> 4;             // 0..15
    const int abs_slice = blockIdx.y * 2 + sl;   // 0..11
    const int qkv  = abs_slice >> 2;
    const int head = abs_slice & 3;
    u16* dbase = QKVH + ((size_t)(z * NHEADS + head) * HWSZ) * 192 + qkv * 64 + c * 8;
    #pragma unroll
    for (int pass = 0; pass < 8; ++pass) {
        const int px = px0 + pass * 16;
        const uint4 val = *reinterpret_cast<const uint4*>(
            &Ct[(sl * 128 + px) * CTP + c * 8]);
        *reinterpret_cast<uint4*>(dbase + (size_t)(p0 + px) * 192) = val;
    }
}

// ---------------------------------------------------------------------------
// Dilated neighborhood attention on QKVH [(z*4+head)][p][q64|k64|v64] bf16.
// 8 threads per position (8 channels each); scores combined via
// __shfl_xor(.,1/2/4); softmax redundant per octet; PV per 8 channels.
// k loads batch-issued; v loads issued before softmax (latency hiding).
// XCD-aware blockIdx.x swizzle. OOB: score exactly 0 in softmax, zero v.
// ---------------------------------------------------------------------------
__global__ __launch_bounds__(256) void attn8(
    const u16* __restrict__ QKVH, u16* __restrict__ YT)
{
    const int hi  = blockIdx.y;
    const int tid = threadIdx.x;
    const int bxr = blockIdx.x;                       // 0..511
    const int bx  = (bxr & 7) * 64 + (bxr >> 3);      // XCD-contiguous bands
    const int p   = bx * 32 + (tid >> 3);
    const int oct = tid & 7;                          // 8-ch slice
    const int yy = p >> 7;
    const int xx = p & 127;
    const int r  = hi + 1;

    const u16* base = QKVH +
        ((size_t)(blockIdx.z * NHEADS + hi) * HWSZ) * 192;

    // q octet (8 channels) -> fp32 regs
    const uint4 qv = *reinterpret_cast<const uint4*>(
        base + (size_t)p * 192 + oct * 8);
    float qf[8];
    {
        const unsigned wv[4] = {qv.x, qv.y, qv.z, qv.w};
        #pragma unroll
        for (int d = 0; d < 4; ++d) {
            qf[d * 2 + 0] = __uint_as_float(wv[d] << 16);
            qf[d * 2 + 1] = __uint_as_float(wv[d] & 0xffff0000u);
        }
    }

    int   offs[9];
    float valid[9];
    #pragma unroll
    for (int n = 0; n < 9; ++n) {
        const int dy = (n / 3 - 1) * r;
        const int dx = (n % 3 - 1) * r;
        const int y2 = yy + dy, x2 = xx + dx;
        const bool ok = (y2 >= 0) && (y2 < HH) && (x2 >= 0) && (x2 < WW);
        valid[n] = ok ? 1.f : 0.f;
        const int y2c = min(max(y2, 0), HH - 1);
        const int x2c = min(max(x2, 0), WW - 1);
        offs[n] = y2c * WW + x2c;
    }

    // Batch-issue all 9 k loads (independent -> 9 outstanding VMEM ops)
    uint4 kb[9];
    #pragma unroll
    for (int n = 0; n < 9; ++n)
        kb[n] = *reinterpret_cast<const uint4*>(
            base + (size_t)offs[n] * 192 + 64 + oct * 8);

    float sc[9];
    #pragma unroll
    for (int n = 0; n < 9; ++n) {
        const unsigned wv[4] = {kb[n].x, kb[n].y, kb[n].z, kb[n].w};
        float s = 0.f;
        #pragma unroll
        for (int d = 0; d < 4; ++d) {
            s += qf[d * 2 + 0] * __uint_as_float(wv[d] << 16);
            s += qf[d * 2 + 1] * __uint_as_float(wv[d] & 0xffff0000u);
        }
        sc[n] = s;
    }
    #pragma unroll
    for (int n = 0; n < 9; ++n) {
        sc[n] += __shfl_xor(sc[n], 1);
        sc[n] += __shfl_xor(sc[n], 2);
        sc[n] += __shfl_xor(sc[n], 4);
        sc[n] *= valid[n];
    }

    // Issue all 9 v loads NOW — latency hides under the softmax below.
    uint4 vb[9];
    #pragma unroll
    for (int n = 0; n < 9; ++n)
        vb[n] = *reinterpret_cast<const uint4*>(
            base + (size_t)offs[n] * 192 + 128 + oct * 8);

    float m = sc[0];
    #pragma unroll
    for (int n = 1; n < 9; ++n) m = fmaxf(m, sc[n]);
    float wgt[9], den = 0.f;
    #pragma unroll
    for (int n = 0; n < 9; ++n) { wgt[n] = __expf(sc[n] - m); den += wgt[n]; }
    const float inv = 1.f / den;
    #pragma unroll
    for (int n = 0; n < 9; ++n) wgt[n] *= inv * valid[n];

    // PV for this thread's 8 channels
    float a[8];
    #pragma unroll
    for (int d = 0; d < 8; ++d) a[d] = 0.f;
    #pragma unroll
    for (int n = 0; n < 9; ++n) {
        const unsigned wv[4] = {vb[n].x, vb[n].y, vb[n].z, vb[n].w};
        const float wn_ = wgt[n];
        #pragma unroll
        for (int d = 0; d < 4; ++d) {
            a[d * 2 + 0] += wn_ * __uint_as_float(wv[d] << 16);
            a[d * 2 + 1] += wn_ * __uint_as_float(wv[d] & 0xffff0000u);
        }
    }

    u16* outp = YT + ((size_t)blockIdx.z * HWSZ + p) * CCH
                   + hi * DHEAD + oct * 8;
    uint4 st;
    st.x = pack2(a[0], a[1]);
    st.y = pack2(a[2], a[3]);
    st.z = pack2(a[4], a[5]);
    st.w = pack2(a[6], a[7]);
    *reinterpret_cast<uint4*>(outp) = st;
}

// ---------------------------------------------------------------------------
// Proj MFMA GEMM + fused BN partials: D[o][p] = sum_k WP[o][k] * YT[p][k].
// XCD-aware p-tile swizzle. Writes YP bf16 [batch][o][p] and per-(channel,
// 64px-block) (sum,sumsq) partials (slot = swizzled tile, bijective).
// (Round-18 proven configuration: single buffer, 2 barriers per K-step.)
// ---------------------------------------------------------------------------
__global__ __launch_bounds__(256) void gemm_proj(
    const u16* __restrict__ A, const u16* __restrict__ B,
    u16* __restrict__ YP, long long b_zs,
    float* __restrict__ part, int batch0)
{
    constexpr int BK = 64;
    __shared__ u16 As[128 * BK];
    __shared__ u16 Bs[128 * BK];

    const int tid  = threadIdx.x;
    const int lane = tid & 63;
    const int w    = tid >> 6;
    const int wm   = w >> 1, wn = w & 1;
    const int o0   = blockIdx.y * 128;
    const int pt   = ((blockIdx.x & 7) << 4) | (blockIdx.x >> 3);  // bijective
    const int p0   = pt * 128;
    const u16* Bz  = B + (size_t)blockIdx.z * b_zs;

    const int srow  = lane >> 3;
    const int sslot = (lane & 7) ^ srow;

    auto stage = [&](int c0) {
        #pragma unroll
        for (int j = 0; j < 4; ++j) {
            const int q = w * 4 + j;
            const int r = q * 8 + srow;
            gl_lds16(A  + (size_t)(o0 + r) * KDIM + c0 + sslot * 8, As + q * 512);
            gl_lds16(Bz + (size_t)(p0 + r) * KDIM + c0 + sslot * 8, Bs + q * 512);
        }
    };

    f32x4 acc[4][4];
    #pragma unroll
    for (int m = 0; m < 4; ++m)
        #pragma unroll
        for (int n = 0; n < 4; ++n)
            acc[m][n] = (f32x4){0.f, 0.f, 0.f, 0.f};

    stage(0);
    #pragma unroll
    for (int kt = 0; kt < KDIM / BK; ++kt) {
        __syncthreads();
        #pragma unroll
        for (int h = 0; h < 2; ++h) {
            bf16x8 af[4], bfr[4];
            #pragma unroll
            for (int m = 0; m < 4; ++m) {
                const int r  = wm * 64 + m * 16 + (lane & 15);
                const int sl = ((h << 2) | (lane >> 4)) ^ (r & 7);
                af[m] = *reinterpret_cast<const bf16x8*>(As + r * BK + sl * 8);
            }
            #pragma unroll
            for (int n = 0; n < 4; ++n) {
                const int r  = wn * 64 + n * 16 + (lane & 15);
                const int sl = ((h << 2) | (lane >> 4)) ^ (r & 7);
                bfr[n] = *reinterpret_cast<const bf16x8*>(Bs + r * BK + sl * 8);
            }
            #pragma unroll
            for (int m = 0; m < 4; ++m)
                #pragma unroll
                for (int n = 0; n < 4; ++n)
                    acc[m][n] = __builtin_amdgcn_mfma_f32_16x16x32_bf16(
                        af[m], bfr[n], acc[m][n], 0, 0, 0);
        }
        if (kt + 1 < KDIM / BK) {
            __syncthreads();
            stage((kt + 1) * BK);
        }
    }

    const int g = lane >> 4, ln15 = lane & 15;
    const int batch = batch0 + blockIdx.z;
    u16* Yz = YP + (size_t)batch * CCH * HWSZ;
    float s[4][4], q2[4][4];
    #pragma unroll
    for (int m = 0; m < 4; ++m) {
        const int ow = o0 + wm * 64 + m * 16 + g * 4;
        #pragma unroll
        for (int j = 0; j < 4; ++j) { s[m][j] = 0.f; q2[m][j] = 0.f; }
        #pragma unroll
        for (int n = 0; n < 4; ++n) {
            const int pc = p0 + wn * 64 + n * 16 + ln15;
            #pragma unroll
            for (int j = 0; j < 4; ++j) {
                const float v = acc[m][n][j];
                Yz[(size_t)(ow + j) * PDIM + pc] = f2bf(v);
                s[m][j]  += v;
                q2[m][j] += v * v;
            }
        }
    }
    // reduce over the 16 px-lanes (bits 0..3 of lane)
    #pragma unroll
    for (int mask = 1; mask <= 8; mask <<= 1) {
        #pragma unroll
        for (int m = 0; m < 4; ++m)
            #pragma unroll
            for (int j = 0; j < 4; ++j) {
                s[m][j]  += __shfl_xor(s[m][j],  mask);
                q2[m][j] += __shfl_xor(q2[m][j], mask);
            }
    }
    if (ln15 == 0) {
        const int pxblk = batch * 256 + pt * 2 + wn;   // 64-px block (bijective)
        #pragma unroll
        for (int m = 0; m < 4; ++m) {
            const int ow = o0 + wm * 64 + m * 16 + g * 4;
            #pragma unroll
            for (int j = 0; j < 4; ++j) {
                const size_t idx = ((size_t)(ow + j) * 1024 + pxblk) * 2;
                part[idx]     = s[m][j];
                part[idx + 1] = q2[m][j];
            }
        }
    }
}

// ---------------------------------------------------------------------------
// BN final: per channel, reduce 1024 (sum,sumsq) partials. Deterministic.
// ---------------------------------------------------------------------------
__global__ __launch_bounds__(256) void bn_final(
    const float* __restrict__ part, float* __restrict__ stats)
{
    const int c = blockIdx.x;
    const int tid = threadIdx.x;
    float s = 0.f, q = 0.f;
    #pragma unroll
    for (int it = 0; it < 4; ++it) {
        const int i = tid + it * 256;
        s += part[((size_t)c * 1024 + i) * 2 + 0];
        q += part[((size_t)c * 1024 + i) * 2 + 1];
    }
    __shared__ float sh0[256], sh1[256];
    sh0[tid] = s; sh1[tid] = q;
    __syncthreads();
    for (int st = 128; st > 0; st >>= 1) {
        if (tid < st) { sh0[tid] += sh0[tid + st]; sh1[tid] += sh1[tid + st]; }
        __syncthreads();
    }
    if (tid == 0) {
        const float N = (float)(BATCH * HWSZ);
        const float mean = sh0[0] / N;
        const float var  = sh1[0] / N - mean * mean;
        stats[c]       = mean;
        stats[CCH + c] = rsqrtf(var + 1e-5f);
    }
}

// ---------------------------------------------------------------------------
// Epilogue: out = x + silu( (yp - mean) * invstd * gamma + beta ), yp bf16.
// ---------------------------------------------------------------------------
__global__ __launch_bounds__(256) void bn_silu_res(
    const u16* __restrict__ yp, const float* __restrict__ x,
    const float* __restrict__ stats, const float* __restrict__ gamma,
    const float* __restrict__ beta, float* __restrict__ out)
{
    const size_t i = ((size_t)blockIdx.x * 256 + threadIdx.x) * 8;
    const int c = (int)((i >> 14) & 255);
    const float mean = stats[c];
    const float inv  = stats[CCH + c];
    const float g = gamma[c], bt = beta[c];

    const uint4 yv = *reinterpret_cast<const uint4*>(&yp[i]);
    const unsigned wv[4] = {yv.x, yv.y, yv.z, yv.w};
    float vo[8];
    #pragma unroll
    for (int d = 0; d < 4; ++d) {
        const float y0 = __uint_as_float(wv[d] << 16);
        const float y1 = __uint_as_float(wv[d] & 0xffff0000u);
        const float yn0 = (y0 - mean) * inv * g + bt;
        const float yn1 = (y1 - mean) * inv * g + bt;
        vo[d * 2 + 0] = yn0 / (1.f + __expf(-yn0));
        vo[d * 2 + 1] = yn1 / (1.f + __expf(-yn1));
    }
    const float4 x0 = *reinterpret_cast<const float4*>(&x[i]);
    const float4 x1 = *reinterpret_cast<const float4*>(&x[i + 4]);
    float4 o0, o1;
    o0.x = x0.x + vo[0]; o0.y = x0.y + vo[1];
    o0.z = x0.z + vo[2]; o0.w = x0.w + vo[3];
    o1.x = x1.x + vo[4]; o1.y = x1.y + vo[5];
    o1.z = x1.z + vo[6]; o1.w = x1.w + vo[7];
    *reinterpret_cast<float4*>(&out[i])     = o0;
    *reinterpret_cast<float4*>(&out[i + 4]) = o1;
}

// ---------------------------------------------------------------------------
extern "C" void kernel_launch(void* const* d_in, const int* in_sizes, int n_in,
                              void* d_out, int out_size, void* d_ws, size_t ws_size,
                              hipStream_t stream)
{
    const float* x      = (const float*)d_in[0];
    const float* w_qkv  = (const float*)d_in[1];
    const float* w_proj = (const float*)d_in[2];
    const float* gamma  = (const float*)d_in[3];
    const float* beta   = (const float*)d_in[4];
    float* out = (float*)d_out;

    // ws layout:
    //   XT [4][16384][256] bf16 (33.5 MB); YP aliases it (XT is fully dead
    //   once gemm_qkv for those batches has consumed it).
    //   QKVH: [z*4 heads][16384][192]; YT follows QKVH.
    //   Full path (z=4, single pass): 170.4 MB. Pair path (z=2): ~103 MB.
    u16*   XT    = (u16*)d_ws;
    u16*   YP    = XT;                               // alias (see above)
    u16*   WQb   = XT + (size_t)BATCH * HWSZ * CCH;  // [768][256]
    u16*   WPb   = WQb + 768 * CCH;                  // [256][256]
    float* part  = (float*)(WPb + CCH * CCH);        // [256][1024][2] = 2 MB
    float* stats = part + (size_t)CCH * 1024 * 2;    // [512]
    u16*   QKVH  = (u16*)(stats + 512);

    const size_t qkvh_full = (size_t)BATCH * NHEADS * HWSZ * 192;   // 4 batches
    const size_t yt_full   = (size_t)BATCH * HWSZ * CCH;
    u16* YT_full = QKVH + qkvh_full;
    u16* YT_pair = QKVH + qkvh_full / 2;

    const size_t need_full =
        (size_t)((char*)(YT_full + yt_full) - (char*)d_ws);

    // 1) x -> XT (transpose + bf16) with fused weight conversion
    transpose_x<<<dim3(HWSZ / 32, CCH / 32, BATCH), 256, 0, stream>>>(
        x, XT, w_qkv, w_proj, WQb, WPb);

    if (ws_size >= need_full) {
        // 2a) Single pass, z = 4: QKV GEMM -> attention -> proj (+BN partials)
        gemm_qkv<<<dim3(PDIM / 128, 768 / 128, BATCH), 256, 0, stream>>>(
            WQb, XT, QKVH, (long long)HWSZ * CCH);

        attn8<<<dim3(HWSZ / 32, NHEADS, BATCH), 256, 0, stream>>>(QKVH, YT_full);

        gemm_proj<<<dim3(PDIM / 128, CCH / 128, BATCH), 256, 0, stream>>>(
            WPb, YT_full, YP, (long long)HWSZ * CCH, part, 0);
    } else {
        // 2b) Two passes of batch pairs (z = 2), QKVH/YT regions reused.
        for (int pair = 0; pair < 2; ++pair) {
            const u16* Bx = XT + (size_t)pair * 2 * HWSZ * CCH;
            gemm_qkv<<<dim3(PDIM / 128, 768 / 128, 2), 256, 0, stream>>>(
                WQb, Bx, QKVH, (long long)HWSZ * CCH);

            attn8<<<dim3(HWSZ / 32, NHEADS, 2), 256, 0, stream>>>(QKVH, YT_pair);

            gemm_proj<<<dim3(PDIM / 128, CCH / 128, 2), 256, 0, stream>>>(
                WPb, YT_pair, YP, (long long)HWSZ * CCH, part, pair * 2);
        }
    }

    // 3) BN stats from fused partials
    bn_final<<<CCH, 256, 0, stream>>>(part, stats);

    // 4) BN + SiLU + residual: out = x + silu(bn(YP))
    bn_silu_res<<<(unsigned)((size_t)BATCH * CCH * HWSZ / 8 / 256), 256, 0, stream>>>(
        YP, x, stats, gamma, beta, out);
}